// Round 13
// baseline (135.821 us; speedup 1.0000x reference)
//
#include <hip/hip_runtime.h>
#include <hip/hip_fp16.h>
#include <stdint.h>

#define FM_BATCH 16384
#define ND 13
#define NF 26
#define FS 100000
#define FL 2600013            // 26*100000 + 13
#define FL_PAD 2600192        // 10157 * 256

// ws layout: flags [FL_PAD] bytes, fo [16384] int (64 KB), Vt [FL_PAD][16] u32
#define N_MARK  (FM_BATCH * NF)         // 425984
#define WS_FO_OFF   FL_PAD
#define WS_VT_OFF   (FL_PAD + FM_BATCH * 4)
#define WS_CLEAR    (FL_PAD + FM_BATCH * 4)
#define FO_SCALE    1048576.0f          // 2^20 fixed-point for deterministic atomics

// ---- Kernel 0: mark referenced features + accumulate first-order per sample.
// Integer atomicAdd is exactly associative -> deterministic across replays.
__global__ __launch_bounds__(256) void fm_mark(const int* __restrict__ sparse,
                                               const float* __restrict__ w,
                                               unsigned char* __restrict__ flags,
                                               int* __restrict__ fo)
{
    const int t = blockIdx.x * 256 + threadIdx.x;   // t = b*26 + f
    const int f = t % NF;
    const int b = t / NF;
    const int idx = ND + f * FS + sparse[t];
    flags[idx] = 1;
    atomicAdd(&fo[b], __float2int_rn(w[idx] * FO_SCALE));
    if (t < ND) flags[t] = 1;                       // dense features always present
}

// ---- Kernel 1: transpose + fp16-quantize referenced columns of V (R10 form).
// Reads unconditional, full-wave coalesced dword, 32 loads in flight/thread,
// no nt hint (L3 residency across replays is valuable). cvt+store flag-gated.
__global__ __launch_bounds__(256) void fm_prep(const float* __restrict__ V,
                                               const unsigned char* __restrict__ flags,
                                               unsigned* __restrict__ Vt)
{
    const int j = blockIdx.x * 256 + threadIdx.x;
    const bool in = (j < FL);
    const bool fl = in && (flags[j] != 0);

    float va[32];
#pragma unroll
    for (int r = 0; r < 32; ++r)
        va[r] = in ? V[(size_t)r * FL + j] : 0.f;

    // keep the loads un-sunk: force all 32 values live regardless of fl
#pragma unroll
    for (int r = 0; r < 32; ++r)
        asm volatile("" :: "v"(va[r]));

    if (!fl) return;

    unsigned pk[16];
#pragma unroll
    for (int r = 0; r < 16; ++r)
        pk[r] = (unsigned)__half_as_ushort(__float2half_rn(va[2 * r])) |
                ((unsigned)__half_as_ushort(__float2half_rn(va[2 * r + 1])) << 16);

    unsigned* dst = Vt + (size_t)j * 16;
#pragma unroll
    for (int c = 0; c < 4; ++c)
        *(uint4*)(dst + 4 * c) = make_uint4(pk[4 * c], pk[4 * c + 1],
                                            pk[4 * c + 2], pk[4 * c + 3]);
}

// ---- Kernel 2: second-order gather. 32 lanes/sample = 16 k-lanes x 2 halves.
// w[idx] loads removed (folded into fm_mark) -> ~40% fewer scattered requests.
// Dense features balanced across the two divergent half-groups (7/6).
__global__ __launch_bounds__(256) void fm_gather(
    const float* __restrict__ dense,   // [BATCH][13]
    const int*   __restrict__ sparse,  // [BATCH][26]
    const float* __restrict__ w0,      // [1]
    const float* __restrict__ w,       // [FL] (dense part only; L1-hot)
    const int*   __restrict__ fo,      // [BATCH] fixed-point first-order sums
    const unsigned* __restrict__ Vt,   // [FL_PAD][16] u32 (32 fp16)
    float* __restrict__ out)           // [BATCH]
{
    const int tid = blockIdx.x * 256 + threadIdx.x;
    const int b = tid >> 5;            // sample
    const int lane32 = tid & 31;
    const int q = lane32 & 15;         // k-pair slot: ks {2q, 2q+1}
    const int h = lane32 >> 4;         // field half

    float L0 = 0.f, L1 = 0.f, S0 = 0.f, S1 = 0.f, first = 0.f;
    const float* __restrict__ db = dense + b * ND;
    const int*   __restrict__ sb = sparse + b * NF;

    if (h == 0) {
#pragma unroll
        for (int d = 0; d < 7; ++d) {
            const float x = db[d];
            const unsigned r = Vt[(size_t)d * 16 + q];
            const float2 v = __half22float2(*(const __half2*)&r);
            first += x * w[d];
            const float a = x * v.x, c = x * v.y;
            L0 += a; S0 += a * a;
            L1 += c; S1 += c * c;
        }
    } else {
#pragma unroll
        for (int d = 7; d < ND; ++d) {
            const float x = db[d];
            const unsigned r = Vt[(size_t)d * 16 + q];
            const float2 v = __half22float2(*(const __half2*)&r);
            first += x * w[d];
            const float a = x * v.x, c = x * v.y;
            L0 += a; S0 += a * a;
            L1 += c; S1 += c * c;
        }
    }

    // 13 sparse fields per half; all loads independent -> in flight together
    const int f0 = h * 13;
#pragma unroll
    for (int ff = 0; ff < 13; ++ff) {
        const int f = f0 + ff;
        const int idx = ND + f * FS + sb[f];
        const unsigned r = Vt[(size_t)idx * 16 + q];
        const float2 v = __half22float2(*(const __half2*)&r);
        L0 += v.x; S0 += v.x * v.x;
        L1 += v.y; S1 += v.y * v.y;
    }

    // combine the two field-halves per k (xor 16 swaps halves)
    L0 += __shfl_xor(L0, 16);  S0 += __shfl_xor(S0, 16);
    L1 += __shfl_xor(L1, 16);  S1 += __shfl_xor(S1, 16);
    first += __shfl_xor(first, 16);

    float t = L0 * L0 - S0 + L1 * L1 - S1;
    t += __shfl_xor(t, 1);
    t += __shfl_xor(t, 2);
    t += __shfl_xor(t, 4);
    t += __shfl_xor(t, 8);             // sum over the 16 q-lanes

    if (lane32 == 0) {
        const float z = first + w0[0] + (float)fo[b] * (1.0f / FO_SCALE) + 0.5f * t;
        out[b] = 1.f / (1.f + __expf(-z));
    }
}

extern "C" void kernel_launch(void* const* d_in, const int* in_sizes, int n_in,
                              void* d_out, int out_size, void* d_ws, size_t ws_size,
                              hipStream_t stream) {
    const float* dense  = (const float*)d_in[0];
    const int*   sparse = (const int*)d_in[1];
    const float* w0     = (const float*)d_in[2];
    const float* w      = (const float*)d_in[3];
    const float* V      = (const float*)d_in[4];
    float* out = (float*)d_out;

    unsigned char* flags = (unsigned char*)d_ws;                 // 2.6 MB
    int*           fo    = (int*)((char*)d_ws + WS_FO_OFF);      // 64 KB
    unsigned*      Vt    = (unsigned*)((char*)d_ws + WS_VT_OFF); // 166 MB

    hipMemsetAsync(d_ws, 0, WS_CLEAR, stream);                   // flags + fo
    fm_mark<<<N_MARK / 256, 256, 0, stream>>>(sparse, w, flags, fo);
    fm_prep<<<FL_PAD / 256, 256, 0, stream>>>(V, flags, Vt);
    fm_gather<<<(FM_BATCH * 32) / 256, 256, 0, stream>>>(
        dense, sparse, w0, w, fo, Vt, out);
}

// Round 14
// 102.332 us; speedup vs baseline: 1.3273x; 1.3273x over previous
//
#include <hip/hip_runtime.h>
#include <hip/hip_fp16.h>
#include <stdint.h>

#define FM_BATCH 16384
#define ND 13
#define NF 26
#define FS 100000
#define FL 2600013            // 26*100000 + 13
#define FL_PAD 2600192        // 10157 * 256

// ws layout: flags [FL_PAD] bytes (2.6 MB), then Vt [FL_PAD][16] u32 (166 MB)
#define N_MARK  (FM_BATCH * NF)         // 425984

// ---- Kernel 0: mark referenced features (races write the same value 1) ----
__global__ __launch_bounds__(256) void fm_mark(const int* __restrict__ sparse,
                                               unsigned char* __restrict__ flags)
{
    const int t = blockIdx.x * 256 + threadIdx.x;   // t = b*26 + f, flat over sparse
    const int f = t % NF;
    flags[ND + f * FS + sparse[t]] = 1;
    if (t < ND) flags[t] = 1;                       // dense features always present
}

// ---- Kernel 1: transpose + fp16-quantize referenced columns of V ----
// LDS-staged variant: each wave reads 8 whole ROWS of the block's 256-column
// panel as 4 back-to-back dword instructions per row (1 KB sequential run,
// 32 loads in flight per thread - same width/ILP as the R10 champion, only
// the address ORDER changes from 32 interleaved strided streams to long
// sequential runs). fp32 staged to LDS [col][row] (pad 36 -> 16B-aligned
// column reads), then per-column fp16 pack + flag-gated 64 B record store.
__global__ __launch_bounds__(256) void fm_prep(const float* __restrict__ V,
                                               const unsigned char* __restrict__ flags,
                                               unsigned* __restrict__ Vt)
{
    __shared__ float stage[256][36];   // 36.9 KB; pad 36: col base 144 B (16B-aligned)
    const int j0 = blockIdx.x * 256;
    const int t = threadIdx.x;
    const int w = t >> 6, l = t & 63;

    float va[8][4];
    if (j0 + 256 <= FL) {
#pragma unroll
        for (int p = 0; p < 8; ++p) {               // rows w, w+4, ..., w+28
            const float* rp = V + (size_t)(w + 4 * p) * FL + j0;
#pragma unroll
            for (int i = 0; i < 4; ++i)
                va[p][i] = rp[i * 64 + l];
        }
    } else {
        // tail panel (one block): per-element guard
#pragma unroll
        for (int p = 0; p < 8; ++p) {
#pragma unroll
            for (int i = 0; i < 4; ++i) {
                const int j = j0 + i * 64 + l;
                va[p][i] = (j < FL) ? V[(size_t)(w + 4 * p) * FL + j] : 0.f;
            }
        }
    }

#pragma unroll
    for (int p = 0; p < 8; ++p)
#pragma unroll
        for (int i = 0; i < 4; ++i)
            stage[i * 64 + l][w + 4 * p] = va[p][i];
    __syncthreads();

    const int j = j0 + t;
    if (j < FL && flags[j]) {
        unsigned pk[16];
#pragma unroll
        for (int r = 0; r < 16; ++r)
            pk[r] = (unsigned)__half_as_ushort(__float2half_rn(stage[t][2 * r])) |
                    ((unsigned)__half_as_ushort(__float2half_rn(stage[t][2 * r + 1])) << 16);
        unsigned* dst = Vt + (size_t)j * 16;
#pragma unroll
        for (int c = 0; c < 4; ++c)
            *(uint4*)(dst + 4 * c) = make_uint4(pk[4 * c], pk[4 * c + 1],
                                                pk[4 * c + 2], pk[4 * c + 3]);
    }
}

// ---- Kernel 2: the whole FM. 32 lanes/sample = 16 k-lanes x 2 field-halves.
// 2048 blocks -> 32 waves/CU (max occupancy). (R11 champion form, unchanged.)
__global__ __launch_bounds__(256) void fm_gather(
    const float* __restrict__ dense,   // [BATCH][13]
    const int*   __restrict__ sparse,  // [BATCH][26]
    const float* __restrict__ w0,      // [1]
    const float* __restrict__ w,       // [FL]
    const unsigned* __restrict__ Vt,   // [FL_PAD][16] u32 (32 fp16)
    float* __restrict__ out)           // [BATCH]
{
    const int tid = blockIdx.x * 256 + threadIdx.x;
    const int b = tid >> 5;            // sample
    const int lane32 = tid & 31;
    const int q = lane32 & 15;         // k-pair slot: ks {2q, 2q+1}
    const int h = lane32 >> 4;         // field half

    float L0 = 0.f, L1 = 0.f, S0 = 0.f, S1 = 0.f, first = 0.f;
    const float* __restrict__ db = dense + b * ND;
    const int*   __restrict__ sb = sparse + b * NF;

    if (h == 0) {
#pragma unroll
        for (int d = 0; d < ND; ++d) {
            const float x = db[d];
            const unsigned r = Vt[(size_t)d * 16 + q];
            const float2 v = __half22float2(*(const __half2*)&r);
            first += x * w[d];
            const float a = x * v.x, c = x * v.y;
            L0 += a; S0 += a * a;
            L1 += c; S1 += c * c;
        }
    }

    const int f0 = h * 13;
#pragma unroll
    for (int ff = 0; ff < 13; ++ff) {
        const int f = f0 + ff;
        const int idx = ND + f * FS + sb[f];
        const unsigned r = Vt[(size_t)idx * 16 + q];
        const float2 v = __half22float2(*(const __half2*)&r);
        first += w[idx];               // same addr across the 16 q-lanes -> broadcast
        L0 += v.x; S0 += v.x * v.x;
        L1 += v.y; S1 += v.y * v.y;
    }

    // combine the two field-halves per k (xor 16 swaps halves)
    L0 += __shfl_xor(L0, 16);  S0 += __shfl_xor(S0, 16);
    L1 += __shfl_xor(L1, 16);  S1 += __shfl_xor(S1, 16);
    first += __shfl_xor(first, 16);

    float t = L0 * L0 - S0 + L1 * L1 - S1;
    t += __shfl_xor(t, 1);
    t += __shfl_xor(t, 2);
    t += __shfl_xor(t, 4);
    t += __shfl_xor(t, 8);             // sum over the 16 q-lanes

    if (lane32 == 0) {
        const float z = first + w0[0] + 0.5f * t;
        out[b] = 1.f / (1.f + __expf(-z));
    }
}

extern "C" void kernel_launch(void* const* d_in, const int* in_sizes, int n_in,
                              void* d_out, int out_size, void* d_ws, size_t ws_size,
                              hipStream_t stream) {
    const float* dense  = (const float*)d_in[0];
    const int*   sparse = (const int*)d_in[1];
    const float* w0     = (const float*)d_in[2];
    const float* w      = (const float*)d_in[3];
    const float* V      = (const float*)d_in[4];
    float* out = (float*)d_out;

    unsigned char* flags = (unsigned char*)d_ws;              // 2.6 MB
    unsigned*      Vt    = (unsigned*)((char*)d_ws + FL_PAD); // 166 MB, 256B-aligned

    hipMemsetAsync(flags, 0, FL_PAD, stream);                 // graph-capturable
    fm_mark<<<N_MARK / 256, 256, 0, stream>>>(sparse, flags);
    fm_prep<<<FL_PAD / 256, 256, 0, stream>>>(V, flags, Vt);
    fm_gather<<<(FM_BATCH * 32) / 256, 256, 0, stream>>>(
        dense, sparse, w0, w, Vt, out);
}